// Round 10
// baseline (1408.125 us; speedup 1.0000x reference)
//
#include <hip/hip_runtime.h>

typedef __attribute__((ext_vector_type(8))) short bf16x8;
typedef __attribute__((ext_vector_type(4))) float f32x4;
typedef const __attribute__((address_space(1))) void* gas_ptr;
typedef __attribute__((address_space(3))) void* las_ptr;

__device__ __forceinline__ unsigned short f2bf(float f) {
  unsigned int u = __float_as_uint(f);
  return (unsigned short)((u + 0x7fffu + ((u >> 16) & 1u)) >> 16);  // RNE
}
__device__ __forceinline__ unsigned int cvt_pk_bf16(float a, float b) {
  unsigned int r;
  asm volatile("v_cvt_pk_bf16_f32 %0, %1, %2" : "=v"(r) : "v"(a), "v"(b));
  return r;
}
__device__ __forceinline__ float sigm(float x) { return 1.0f / (1.0f + __expf(-x)); }

// device-coherent (sc0 sc1) store: relaxed agent atomic bypasses L1/L2, lands at IF.
__device__ __forceinline__ void st_cv(unsigned int* p, unsigned int v) {
  __hip_atomic_store(p, v, __ATOMIC_RELAXED, __HIP_MEMORY_SCOPE_AGENT);
}

// ---- fence-free two-level grid barrier, MONOTONE master (no sense hop) ----
// 16 leaf lines (16 RMWs each, reset per phase) -> master line (16 RMWs/phase, monotone).
// Pollers (256 thread-0s) read master directly: master >= 16*phase. Writers/pollers stay
// on separate roles; poll population is thread-0-only (R8 lesson).
__device__ __forceinline__ void gbar_arrive(int* bars, int bid) {
  int* leaf = bars + (bid & 15) * 32;
  int* mcnt = bars + 512;
  if (__hip_atomic_fetch_add(leaf, 1, __ATOMIC_RELAXED, __HIP_MEMORY_SCOPE_AGENT) == 15) {
    __hip_atomic_store(leaf, 0, __ATOMIC_RELAXED, __HIP_MEMORY_SCOPE_AGENT);
    __hip_atomic_fetch_add(mcnt, 1, __ATOMIC_RELAXED, __HIP_MEMORY_SCOPE_AGENT);
  }
}
__device__ __forceinline__ void gbar_wait(int* bars, int target) {
  int* mcnt = bars + 512;
  const int tgt = 16 * target;
  while (__hip_atomic_load(mcnt, __ATOMIC_RELAXED, __HIP_MEMORY_SCOPE_AGENT) < tgt)
    __builtin_amdgcn_s_sleep(1);
}

// ---------------- K1: h0 -> bf16 double-buffered state, zero barrier ----------------
__global__ __launch_bounds__(256) void init_kernel(
    const float* __restrict__ h0_in,
    unsigned short* __restrict__ h0buf, unsigned short* __restrict__ h1buf,
    int* __restrict__ bar)
{
  const int j = blockIdx.x * 256 + threadIdx.x;   // 0..32767
  if (j < 768) bar[j] = 0;
  h0buf[j] = f2bf(h0_in[j]);                 // layer0 h -> h0buf slot0
  h1buf[32768 + j] = f2bf(h0_in[32768 + j]); // layer1 h -> h1buf slot1
}

// ---------------- K1b: gather emb[tokens] -> xemb bf16 [128*32][1024] ----------------
__global__ __launch_bounds__(256) void gather_emb(
    const int* __restrict__ tokens, const float* __restrict__ etab,
    unsigned short* __restrict__ xemb)
{
  const int r = blockIdx.x;                       // t*32 + b
  const float* src = etab + (size_t)tokens[r] * 1024;
  const int q = threadIdx.x * 4;
  const float4 v = *(const float4*)(src + q);
  uint2 o;
  o.x = cvt_pk_bf16(v.x, v.y);
  o.y = cvt_pk_bf16(v.z, v.w);
  *(uint2*)(xemb + (size_t)r * 1024 + q) = o;
}

// ---------------- K2: lstm_W -> per-block MFMA-fragment-slot images (bf16) ----------------
__global__ __launch_bounds__(256) void reorg_lstm_w(
    const float* __restrict__ W, char* __restrict__ wimg)
{
  __shared__ float tile[64 * 36];
  const int bid = blockIdx.x;            // 256 = lstm block id
  const int layer = bid >> 7;
  const int u0 = (bid & 127) * 8;
  const int tid = threadIdx.x;
  const float* Wl = W + (size_t)layer * 2048 * 4096;
  char* img = wimg + (size_t)bid * 131072;
  const int kl = tid >> 2, g = tid & 3;                                  // load map
  const int row = tid & 15, ksub = (tid >> 4) & 3;                       // emit map
  const int tn = (tid >> 6) & 1, kl2 = tid >> 7;
  const int c = tn * 16 + row;
#pragma unroll 1
  for (int kt = 0; kt < 32; ++kt) {
    const float* src = Wl + (size_t)(kt * 64 + kl) * 4096 + g * 1024 + u0;
    const float4 v0 = *(const float4*)src;
    const float4 v1 = *(const float4*)(src + 4);
    *(float4*)(tile + kl * 36 + g * 8) = v0;
    *(float4*)(tile + kl * 36 + g * 8 + 4) = v1;
    __syncthreads();
    const int kbase = kl2 * 32 + ksub * 8;
    uint4 u;
    u.x = cvt_pk_bf16(tile[(kbase + 0) * 36 + c], tile[(kbase + 1) * 36 + c]);
    u.y = cvt_pk_bf16(tile[(kbase + 2) * 36 + c], tile[(kbase + 3) * 36 + c]);
    u.z = cvt_pk_bf16(tile[(kbase + 4) * 36 + c], tile[(kbase + 5) * 36 + c]);
    u.w = cvt_pk_bf16(tile[(kbase + 6) * 36 + c], tile[(kbase + 7) * 36 + c]);
    const int S = (kt * 2 + kl2) * 128 + tn * 64 + ksub * 16 + row;
    *(uint4*)(img + (size_t)S * 16) = u;
    __syncthreads();
  }
}

// ---------------- K3: pipelined 2-layer LSTM scan ----------------
// Identical to R9 except the barrier: monotone master poll (no sense hop).
__global__ __launch_bounds__(512, 1) void lstm_seq_kernel(
    const char* __restrict__ wimg, const float* __restrict__ bias,
    const float* __restrict__ c0_in,
    const unsigned short* __restrict__ xemb,
    unsigned short* __restrict__ h0buf, unsigned short* __restrict__ h1buf,
    unsigned short* __restrict__ hseq,
    float* __restrict__ out_tail, int* __restrict__ bar)
{
  __shared__ __align__(16) char smem[148608];
  char* wlds   = smem;                        // 131072: W fragment slots
  float* red   = (float*)(smem + 131072);     //  12288: K-quarter partials
  float* gates = (float*)(smem + 143360);     //   4224: [32 b][33] padded
  float* cl    = (float*)(smem + 147584);     //   1024: c-state [32 b][8 u]

  const int tid = threadIdx.x;
  const int bid = blockIdx.x;
  const int layer = bid >> 7;
  const int u0 = (bid & 127) * 8;
  const int lane = tid & 63, w = tid >> 6;
  const int tb = w & 1, kq = w >> 1;
  const int row = tb * 16 + (lane & 15);
  const int kg = lane >> 4;
  unsigned short* hmy = layer ? h1buf : h0buf;
  const bool statx = (layer == 0) && (kq < 2);   // static xemb operand (prefetchable)

  // one-time: W image -> LDS (linear 16B, coalesced), c-state -> LDS
  {
    const char* img = wimg + (size_t)bid * 131072;
#pragma unroll 1
    for (int i = 0; i < 16; ++i) {
      const int off = (i * 512 + tid) * 16;
      __builtin_amdgcn_global_load_lds((gas_ptr)(img + off), (las_ptr)(wlds + off), 16, 0, 0);
    }
    if (tid < 256) cl[tid] = c0_in[layer * 32768 + (tid >> 3) * 1024 + u0 + (tid & 7)];
  }
  const int cc = lane & 15;
  const float biasv0 = bias[layer * 4096 + (cc >> 3) * 1024 + u0 + (cc & 7)];         // tn=0 col
  const float biasv1 = bias[layer * 4096 + ((cc + 16) >> 3) * 1024 + u0 + (cc & 7)];  // tn=1 col
  asm volatile("s_waitcnt vmcnt(0)");
  __syncthreads();

  const char* wq = wlds + (size_t)(kq * 16 * 128 + lane) * 16;

  bf16x8 a[16];
  if (statx) {  // prefetch t=0 fragments (plain cached loads; xemb is static)
    const char* xn = (const char*)xemb + row * 2048 + kq * 1024 + kg * 16;
#pragma unroll
    for (int j = 0; j < 16; ++j) a[j] = *(const bf16x8*)(xn + j * 64);
  }

  for (int p = 0; p <= 128; ++p) {
    const bool active = layer ? (p >= 1) : (p < 128);
    if (active) {
      const int t = layer ? (p - 1) : p;
      f32x4 acc0 = {0.f, 0.f, 0.f, 0.f}, acc1 = {0.f, 0.f, 0.f, 0.f};

      if (!statx) {
        // coherent x: layer0 kq>=2 -> own h0; layer1: kq<2 -> h0, kq>=2 -> own h1
        const char* src = (layer && kq < 2) ? (const char*)h0buf : (const char*)hmy;
        const char* xb = src + (p & 1) * 65536 + row * 2048 + (kq & 1) * 1024 + kg * 16;
#pragma unroll
        for (int j = 0; j < 16; ++j)
          asm volatile("global_load_dwordx4 %0, %1, off sc0 sc1"
                       : "=v"(a[j]) : "v"(xb + j * 64) : "memory");
        auto mm4 = [&](int j0) {
#pragma unroll
          for (int j = j0; j < j0 + 4; ++j) {
            const bf16x8 b0 = *(const bf16x8*)(wq + (size_t)j * 2048);
            const bf16x8 b1 = *(const bf16x8*)(wq + (size_t)j * 2048 + 1024);
            acc0 = __builtin_amdgcn_mfma_f32_16x16x32_bf16(a[j], b0, acc0, 0, 0, 0);
            acc1 = __builtin_amdgcn_mfma_f32_16x16x32_bf16(a[j], b1, acc1, 0, 0, 0);
          }
        };
        asm volatile("s_waitcnt vmcnt(12)" ::: "memory");
        __builtin_amdgcn_sched_barrier(0);  // rule #18: keep MFMAs below their wait
        mm4(0);
        asm volatile("s_waitcnt vmcnt(8)" ::: "memory");
        __builtin_amdgcn_sched_barrier(0);
        mm4(4);
        asm volatile("s_waitcnt vmcnt(4)" ::: "memory");
        __builtin_amdgcn_sched_barrier(0);
        mm4(8);
        asm volatile("s_waitcnt vmcnt(0)" ::: "memory");
        __builtin_amdgcn_sched_barrier(0);
        mm4(12);
      } else {
#pragma unroll
        for (int j = 0; j < 16; ++j) {
          const bf16x8 b0 = *(const bf16x8*)(wq + (size_t)j * 2048);
          const bf16x8 b1 = *(const bf16x8*)(wq + (size_t)j * 2048 + 1024);
          acc0 = __builtin_amdgcn_mfma_f32_16x16x32_bf16(a[j], b0, acc0, 0, 0, 0);
          acc1 = __builtin_amdgcn_mfma_f32_16x16x32_bf16(a[j], b1, acc1, 0, 0, 0);
        }
      }

      // 4-way K-quarter reduction: kq>0 waves dump, kq==0 waves sum + bias -> gates
      if (kq > 0) {
        const int s0 = (((kq - 1) * 2 + tb) * 2 + 0) * 64 + lane;
        const int s1 = (((kq - 1) * 2 + tb) * 2 + 1) * 64 + lane;
        *(f32x4*)(red + s0 * 4) = acc0;
        *(f32x4*)(red + s1 * 4) = acc1;
      }
      __syncthreads();
      if (kq == 0) {
#pragma unroll
        for (int q = 1; q < 4; ++q) {
          const f32x4 o0 = *(const f32x4*)(red + ((((q - 1) * 2 + tb) * 2 + 0) * 64 + lane) * 4);
          const f32x4 o1 = *(const f32x4*)(red + ((((q - 1) * 2 + tb) * 2 + 1) * 64 + lane) * 4);
#pragma unroll
          for (int r = 0; r < 4; ++r) { acc0[r] += o0[r]; acc1[r] += o1[r]; }
        }
        const int rb = tb * 16 + kg * 4;
#pragma unroll
        for (int r = 0; r < 4; ++r) {
          gates[(rb + r) * 33 + cc] = acc0[r] + biasv0;
          gates[(rb + r) * 33 + 16 + cc] = acc1[r] + biasv1;
        }
      }
      __syncthreads();
      // cell update: 128 threads x 2 units; c-state in LDS; h stored as coherent dword
      if (tid < 128) {
        const int cb = tid >> 2, up = (tid & 3) * 2;
        const float gi0 = gates[cb * 33 + up],      gi1 = gates[cb * 33 + up + 1];
        const float gj0 = gates[cb * 33 + 8 + up],  gj1 = gates[cb * 33 + 9 + up];
        const float gf0 = gates[cb * 33 + 16 + up], gf1 = gates[cb * 33 + 17 + up];
        const float go0 = gates[cb * 33 + 24 + up], go1 = gates[cb * 33 + 25 + up];
        const float cn0 = cl[cb * 8 + up] * sigm(gf0) + sigm(gi0) * tanhf(gj0);
        const float cn1 = cl[cb * 8 + up + 1] * sigm(gf1) + sigm(gi1) * tanhf(gj1);
        const float hn0 = tanhf(cn0) * sigm(go0);
        const float hn1 = tanhf(cn1) * sigm(go1);
        cl[cb * 8 + up] = cn0;
        cl[cb * 8 + up + 1] = cn1;
        const unsigned int pk = cvt_pk_bf16(hn0, hn1);
        st_cv((unsigned int*)(hmy + ((p + 1) & 1) * 32768 + cb * 1024 + u0 + up), pk);
        if (layer) *(unsigned int*)(hseq + (size_t)t * 32768 + cb * 1024 + u0 + up) = pk;
        if (t == 127) {
          float* ot = out_tail + layer * 32768 + cb * 1024 + u0 + up;
          ot[0] = hn0; ot[1] = hn1;                     // h_last
          ot[65536] = cn0; ot[65537] = cn1;             // c_last
        }
      }
    }

    if (p < 128) {
      __syncthreads();  // all LDS consumers done; drains h stores (vmcnt 0) before arrive
      if (tid == 0) gbar_arrive(bar, bid);
      if (statx && (p + 1) < 128) {
        // prefetch next-t xemb frags; they fly during the poll, land at exit syncthreads
        const char* xn = (const char*)xemb + (size_t)(p + 1) * 65536 + row * 2048 + kq * 1024 + kg * 16;
#pragma unroll
        for (int j = 0; j < 16; ++j) a[j] = *(const bf16x8*)(xn + j * 64);
      }
      if (tid == 0) gbar_wait(bar, p + 1);
      __syncthreads();
    }
  }
}

// ---------------- K4: dec_W [1024][32000] f32 -> Wt [32000][1024] bf16 ----------------
__global__ __launch_bounds__(256) void transpose_decw_kernel(
    const float* __restrict__ decW, unsigned short* __restrict__ Wt)
{
  __shared__ float tile[64 * 68];
  const int bid = blockIdx.x;         // 8000 = 16 k-tiles x 500 n-tiles
  const int k0 = (bid & 15) * 64;
  const int n0 = (bid >> 4) * 64;
  const int tid = threadIdx.x;
  {
    const int kl = tid >> 4, c4 = (tid & 15) * 4;
#pragma unroll
    for (int i = 0; i < 4; ++i) {
      const int kr = kl + 16 * i;
      *(float4*)(tile + kr * 68 + c4) =
          *(const float4*)(decW + (size_t)(k0 + kr) * 32000 + n0 + c4);
    }
  }
  __syncthreads();
  {
    const int nl = tid >> 3, kc = (tid & 7) * 8;
#pragma unroll
    for (int h2 = 0; h2 < 2; ++h2) {
      const int n = nl + 32 * h2;
      float tv[8];
#pragma unroll
      for (int q = 0; q < 8; ++q) tv[q] = tile[(kc + q) * 68 + n];
      uint4 u;
      u.x = cvt_pk_bf16(tv[0], tv[1]);
      u.y = cvt_pk_bf16(tv[2], tv[3]);
      u.z = cvt_pk_bf16(tv[4], tv[5]);
      u.w = cvt_pk_bf16(tv[6], tv[7]);
      *(uint4*)(Wt + (size_t)(n0 + n) * 1024 + k0 + kc) = u;
    }
  }
}

// ---------------- K5: decoder bf16 MFMA GEMM, 256x256 tile, BK=64, swizzled LDS ----------------
// 2000 blocks x 512 threads (8 waves = 2M x 4N), 2x64KB LDS dbuf, 1 block/CU.
// Per K-tile: stage next tile into other buf (issued early), 4 MFMA sub-phases with
// setprio, ONE syncthreads per tile (its vmcnt0 drain hits ~1-phase-old loads).
// st_16x32 swizzle: same XOR involution on pre-swizzled global source and ds_read addr.
__global__ __launch_bounds__(512, 1) void decoder_kernel(
    const unsigned short* __restrict__ A,   // hseq  [4096][1024] bf16
    const unsigned short* __restrict__ Bt,  // Wt    [32000][1024] bf16 (dec_W^T)
    const float* __restrict__ decb,
    float* __restrict__ out)                // [4096][32000] f32
{
  __shared__ __align__(16) char lds[131072];   // buf b at b*65536: A[256x64] then B[256x64]

  const int bid = blockIdx.x;
  const int swz = (bid & 7) * 250 + (bid >> 3);   // XCD-contiguous (2000 % 8 == 0)
  const int mt = swz / 125, nt = swz % 125;
  const int m0 = mt * 256, n0 = nt * 256;

  const int tid = threadIdx.x;
  const int lane = tid & 63;
  const int wv = tid >> 6;
  const int wm = wv >> 2, wn = wv & 3;            // 2M x 4N waves, out 128x64 each
  const int l15 = lane & 15, kg = lane >> 4;

  f32x4 acc[8][4];
#pragma unroll
  for (int mi = 0; mi < 8; ++mi)
#pragma unroll
    for (int ni = 0; ni < 4; ++ni) {
      f32x4 z = {0.f, 0.f, 0.f, 0.f};
      acc[mi][ni] = z;
    }

  // stage half of tile kt (half 0 = A 256x64, half 1 = B 256x64) into buf kt&1.
  // LDS dest linear; global source pre-swizzled by the st_16x32 involution.
  auto stage4 = [&](int kt, int half) {
    char* bufw = lds + (kt & 1) * 65536 + half * 32768;
    const unsigned short* base = half ? Bt : A;
    const int r0 = half ? n0 : m0;
#pragma unroll
    for (int j = 0; j < 4; ++j) {
      const int o  = (j * 512 + tid) * 16;            // 0..32752, linear LDS offset
      const int os = o ^ (((o >> 9) & 1) << 5);       // swizzled source index
      const int r  = os >> 7, kb = os & 127;          // row, k-byte within 128B row
      const unsigned short* g = base + (size_t)(r0 + r) * 1024 + kt * 64 + kb / 2;
      __builtin_amdgcn_global_load_lds((gas_ptr)g, (las_ptr)(bufw + o), 16, 0, 0);
    }
  };

  stage4(0, 0);
  stage4(0, 1);
  __syncthreads();   // drains vmcnt: tile0 in LDS

  for (int kt = 0; kt < 16; ++kt) {
    const char* bufr = lds + (kt & 1) * 65536;
    bf16x8 bfr[4];
#pragma unroll
    for (int ks = 0; ks < 2; ++ks) {
#pragma unroll
      for (int mh = 0; mh < 2; ++mh) {
        bf16x8 af[4];
#pragma unroll
        for (int q = 0; q < 4; ++q) {                 // A frags mi = mh*4+q
          const int r = wm * 128 + (mh * 4 + q) * 16 + l15;
          const int o = (r * 128 + ks * 64 + kg * 16) ^ (((r >> 2) & 1) << 5);
          af[q] = *(const bf16x8*)(bufr + o);
        }
        if (mh == 0) {
#pragma unroll
          for (int q = 0; q < 4; ++q) {               // B frags ni = q (reused for mh=1)
            const int r = wn * 64 + q * 16 + l15;
            const int o = (r * 128 + ks * 64 + kg * 16) ^ (((r >> 2) & 1) << 5);
            bfr[q] = *(const bf16x8*)(bufr + 32768 + o);
          }
        }
        if (ks == 0 && kt < 15) stage4(kt + 1, mh);   // issue next-tile stages early
        __builtin_amdgcn_s_setprio(1);
#pragma unroll
        for (int q = 0; q < 4; ++q)
#pragma unroll
          for (int ni = 0; ni < 4; ++ni)
            acc[mh * 4 + q][ni] =
                __builtin_amdgcn_mfma_f32_16x16x32_bf16(af[q], bfr[ni], acc[mh * 4 + q][ni], 0, 0, 0);
        __builtin_amdgcn_s_setprio(0);
      }
    }
    __syncthreads();  // per-tile: drains stage loads (vmcnt0) + protects buf swap
  }

#pragma unroll
  for (int ni = 0; ni < 4; ++ni) {
    const int ocol = n0 + wn * 64 + ni * 16 + l15;    // C/D: col = lane&15
    const float bv = decb[ocol];
#pragma unroll
    for (int mi = 0; mi < 8; ++mi) {
      const int orow = m0 + wm * 128 + mi * 16 + kg * 4;  // row = (lane>>4)*4 + reg
#pragma unroll
      for (int r = 0; r < 4; ++r)
        out[(size_t)(orow + r) * 32000 + ocol] = acc[mi][ni][r] + bv;
    }
  }
}

extern "C" void kernel_launch(void* const* d_in, const int* in_sizes, int n_in,
                              void* d_out, int out_size, void* d_ws, size_t ws_size,
                              hipStream_t stream) {
  (void)in_sizes; (void)n_in; (void)out_size; (void)ws_size;
  const int* tokens  = (const int*)d_in[0];
  const float* h0_in = (const float*)d_in[1];
  const float* c0_in = (const float*)d_in[2];
  const float* etab  = (const float*)d_in[3];
  const float* lstmW = (const float*)d_in[4];
  const float* lstmb = (const float*)d_in[5];
  const float* decW  = (const float*)d_in[6];
  const float* decb  = (const float*)d_in[7];
  float* out = (float*)d_out;

  char* ws = (char*)d_ws;
  unsigned short* hseq  = (unsigned short*)(ws + 0);         //  8,388,608 B
  char* img             = ws + 8388608;                      // 33,554,432 B (lstm phase)
  unsigned short* Wt    = (unsigned short*)(ws + 8388608);   // 65,536,000 B (decoder phase, overlaps img+xemb)
  unsigned short* xemb  = (unsigned short*)(ws + 41943040);  //  8,388,608 B (lstm phase)
  unsigned short* h0buf = (unsigned short*)(ws + 73924608);  //    131,072 B (bf16, 2 slots)
  unsigned short* h1buf = (unsigned short*)(ws + 74055680);  //    131,072 B
  int* bar              = (int*)(ws + 74186752);             //      3,072 B

  init_kernel<<<128, 256, 0, stream>>>(h0_in, h0buf, h1buf, bar);
  gather_emb<<<4096, 256, 0, stream>>>(tokens, etab, xemb);
  reorg_lstm_w<<<256, 256, 0, stream>>>(lstmW, img);
  lstm_seq_kernel<<<256, 512, 0, stream>>>(img, lstmb, c0_in, xemb,
                                           h0buf, h1buf, hseq,
                                           out + 131072000, bar);
  transpose_decw_kernel<<<8000, 256, 0, stream>>>(decW, Wt);
  decoder_kernel<<<2000, 512, 0, stream>>>(hseq, Wt, decb, out);
}

// Round 11
// 1397.737 us; speedup vs baseline: 1.0074x; 1.0074x over previous
//
#include <hip/hip_runtime.h>

typedef __attribute__((ext_vector_type(8))) short bf16x8;
typedef __attribute__((ext_vector_type(4))) float f32x4;
typedef __attribute__((ext_vector_type(4))) unsigned int u32x4;
typedef const __attribute__((address_space(1))) void* gas_ptr;
typedef __attribute__((address_space(3))) void* las_ptr;

__device__ __forceinline__ unsigned short f2bf(float f) {
  unsigned int u = __float_as_uint(f);
  return (unsigned short)((u + 0x7fffu + ((u >> 16) & 1u)) >> 16);  // RNE
}
__device__ __forceinline__ unsigned int cvt_pk_bf16(float a, float b) {
  unsigned int r;
  asm volatile("v_cvt_pk_bf16_f32 %0, %1, %2" : "=v"(r) : "v"(a), "v"(b));
  return r;
}
__device__ __forceinline__ float sigm(float x) { return 1.0f / (1.0f + __expf(-x)); }
__device__ __forceinline__ unsigned umin2(unsigned a, unsigned b) { return a < b ? a : b; }

// device-coherent (sc0 sc1) store: relaxed agent atomic bypasses L1/L2, lands at IF.
__device__ __forceinline__ void st_cv(unsigned int* p, unsigned int v) {
  __hip_atomic_store(p, v, __ATOMIC_RELAXED, __HIP_MEMORY_SCOPE_AGENT);
}

// ---- fence-free 2-hop grid barrier: 16 leaf lines (RMW, unpolled) -> 16-word sense array ----
// Polled region receives ONLY plain stores (16/phase, one per leaf winner, monotone values).
// RMWs stay on unpolled leaf lines (R10 lesson: RMW on a polled line serializes with readers).
__device__ __forceinline__ void gbar_arrive(int* bars, int target, int bid) {
  int* leaf  = bars + (bid & 15) * 32;
  int* sense = bars + 640;                       // 16 ints, one 64B region
  if (__hip_atomic_fetch_add(leaf, 1, __ATOMIC_RELAXED, __HIP_MEMORY_SCOPE_AGENT) == 15) {
    __hip_atomic_store(leaf, 0, __ATOMIC_RELAXED, __HIP_MEMORY_SCOPE_AGENT);
    __hip_atomic_store(sense + (bid & 15), target, __ATOMIC_RELAXED, __HIP_MEMORY_SCOPE_AGENT);
  }
}
__device__ __forceinline__ void gbar_wait(int* bars, int target) {
  const unsigned* sense = (const unsigned*)(bars + 640);
  const unsigned tgt = (unsigned)target;
  while (true) {
    u32x4 c0, c1, c2, c3;
    asm volatile(
        "global_load_dwordx4 %0, %4, off sc0 sc1\n\t"
        "global_load_dwordx4 %1, %4, off offset:16 sc0 sc1\n\t"
        "global_load_dwordx4 %2, %4, off offset:32 sc0 sc1\n\t"
        "global_load_dwordx4 %3, %4, off offset:48 sc0 sc1\n\t"
        "s_waitcnt vmcnt(0)"
        : "=v"(c0), "=v"(c1), "=v"(c2), "=v"(c3) : "v"(sense) : "memory");
    const unsigned m01 = umin2(umin2(umin2(c0[0], c0[1]), umin2(c0[2], c0[3])),
                               umin2(umin2(c1[0], c1[1]), umin2(c1[2], c1[3])));
    const unsigned m23 = umin2(umin2(umin2(c2[0], c2[1]), umin2(c2[2], c2[3])),
                               umin2(umin2(c3[0], c3[1]), umin2(c3[2], c3[3])));
    if (umin2(m01, m23) >= tgt) break;
    __builtin_amdgcn_s_sleep(1);
  }
}

// ---------------- K1: h0 -> bf16 double-buffered state, zero barrier ----------------
__global__ __launch_bounds__(256) void init_kernel(
    const float* __restrict__ h0_in,
    unsigned short* __restrict__ h0buf, unsigned short* __restrict__ h1buf,
    int* __restrict__ bar)
{
  const int j = blockIdx.x * 256 + threadIdx.x;   // 0..32767
  if (j < 768) bar[j] = 0;
  h0buf[j] = f2bf(h0_in[j]);                 // layer0 h -> h0buf slot0
  h1buf[32768 + j] = f2bf(h0_in[32768 + j]); // layer1 h -> h1buf slot1
}

// ---------------- K1b: gather emb[tokens] -> xemb bf16 [128*32][1024] ----------------
__global__ __launch_bounds__(256) void gather_emb(
    const int* __restrict__ tokens, const float* __restrict__ etab,
    unsigned short* __restrict__ xemb)
{
  const int r = blockIdx.x;                       // t*32 + b
  const float* src = etab + (size_t)tokens[r] * 1024;
  const int q = threadIdx.x * 4;
  const float4 v = *(const float4*)(src + q);
  uint2 o;
  o.x = cvt_pk_bf16(v.x, v.y);
  o.y = cvt_pk_bf16(v.z, v.w);
  *(uint2*)(xemb + (size_t)r * 1024 + q) = o;
}

// ---------------- K2: lstm_W -> per-block MFMA-fragment-slot images (bf16) ----------------
__global__ __launch_bounds__(256) void reorg_lstm_w(
    const float* __restrict__ W, char* __restrict__ wimg)
{
  __shared__ float tile[64 * 36];
  const int bid = blockIdx.x;            // 256 = lstm block id
  const int layer = bid >> 7;
  const int u0 = (bid & 127) * 8;
  const int tid = threadIdx.x;
  const float* Wl = W + (size_t)layer * 2048 * 4096;
  char* img = wimg + (size_t)bid * 131072;
  const int kl = tid >> 2, g = tid & 3;                                  // load map
  const int row = tid & 15, ksub = (tid >> 4) & 3;                       // emit map
  const int tn = (tid >> 6) & 1, kl2 = tid >> 7;
  const int c = tn * 16 + row;
#pragma unroll 1
  for (int kt = 0; kt < 32; ++kt) {
    const float* src = Wl + (size_t)(kt * 64 + kl) * 4096 + g * 1024 + u0;
    const float4 v0 = *(const float4*)src;
    const float4 v1 = *(const float4*)(src + 4);
    *(float4*)(tile + kl * 36 + g * 8) = v0;
    *(float4*)(tile + kl * 36 + g * 8 + 4) = v1;
    __syncthreads();
    const int kbase = kl2 * 32 + ksub * 8;
    uint4 u;
    u.x = cvt_pk_bf16(tile[(kbase + 0) * 36 + c], tile[(kbase + 1) * 36 + c]);
    u.y = cvt_pk_bf16(tile[(kbase + 2) * 36 + c], tile[(kbase + 3) * 36 + c]);
    u.z = cvt_pk_bf16(tile[(kbase + 4) * 36 + c], tile[(kbase + 5) * 36 + c]);
    u.w = cvt_pk_bf16(tile[(kbase + 6) * 36 + c], tile[(kbase + 7) * 36 + c]);
    const int S = (kt * 2 + kl2) * 128 + tn * 64 + ksub * 16 + row;
    *(uint4*)(img + (size_t)S * 16) = u;
    __syncthreads();
  }
}

// ---------------- K3: pipelined 2-layer LSTM scan ----------------
// R9 structure; barrier = 2-hop leaf->sense-array (poll min-of-16 plain-stored words).
__global__ __launch_bounds__(512, 1) void lstm_seq_kernel(
    const char* __restrict__ wimg, const float* __restrict__ bias,
    const float* __restrict__ c0_in,
    const unsigned short* __restrict__ xemb,
    unsigned short* __restrict__ h0buf, unsigned short* __restrict__ h1buf,
    unsigned short* __restrict__ hseq,
    float* __restrict__ out_tail, int* __restrict__ bar)
{
  __shared__ __align__(16) char smem[148608];
  char* wlds   = smem;                        // 131072: W fragment slots
  float* red   = (float*)(smem + 131072);     //  12288: K-quarter partials
  float* gates = (float*)(smem + 143360);     //   4224: [32 b][33] padded
  float* cl    = (float*)(smem + 147584);     //   1024: c-state [32 b][8 u]

  const int tid = threadIdx.x;
  const int bid = blockIdx.x;
  const int layer = bid >> 7;
  const int u0 = (bid & 127) * 8;
  const int lane = tid & 63, w = tid >> 6;
  const int tb = w & 1, kq = w >> 1;
  const int row = tb * 16 + (lane & 15);
  const int kg = lane >> 4;
  unsigned short* hmy = layer ? h1buf : h0buf;
  const bool statx = (layer == 0) && (kq < 2);   // static xemb operand (prefetchable)

  // one-time: W image -> LDS (linear 16B, coalesced), c-state -> LDS
  {
    const char* img = wimg + (size_t)bid * 131072;
#pragma unroll 1
    for (int i = 0; i < 16; ++i) {
      const int off = (i * 512 + tid) * 16;
      __builtin_amdgcn_global_load_lds((gas_ptr)(img + off), (las_ptr)(wlds + off), 16, 0, 0);
    }
    if (tid < 256) cl[tid] = c0_in[layer * 32768 + (tid >> 3) * 1024 + u0 + (tid & 7)];
  }
  const int cc = lane & 15;
  const float biasv0 = bias[layer * 4096 + (cc >> 3) * 1024 + u0 + (cc & 7)];         // tn=0 col
  const float biasv1 = bias[layer * 4096 + ((cc + 16) >> 3) * 1024 + u0 + (cc & 7)];  // tn=1 col
  asm volatile("s_waitcnt vmcnt(0)");
  __syncthreads();

  const char* wq = wlds + (size_t)(kq * 16 * 128 + lane) * 16;

  bf16x8 a[16];
  if (statx) {  // prefetch t=0 fragments (plain cached loads; xemb is static)
    const char* xn = (const char*)xemb + row * 2048 + kq * 1024 + kg * 16;
#pragma unroll
    for (int j = 0; j < 16; ++j) a[j] = *(const bf16x8*)(xn + j * 64);
  }

  for (int p = 0; p <= 128; ++p) {
    const bool active = layer ? (p >= 1) : (p < 128);
    if (active) {
      const int t = layer ? (p - 1) : p;
      f32x4 acc0 = {0.f, 0.f, 0.f, 0.f}, acc1 = {0.f, 0.f, 0.f, 0.f};

      if (!statx) {
        // coherent x: layer0 kq>=2 -> own h0; layer1: kq<2 -> h0, kq>=2 -> own h1
        const char* src = (layer && kq < 2) ? (const char*)h0buf : (const char*)hmy;
        const char* xb = src + (p & 1) * 65536 + row * 2048 + (kq & 1) * 1024 + kg * 16;
#pragma unroll
        for (int j = 0; j < 16; ++j)
          asm volatile("global_load_dwordx4 %0, %1, off sc0 sc1"
                       : "=v"(a[j]) : "v"(xb + j * 64) : "memory");
        auto mm4 = [&](int j0) {
#pragma unroll
          for (int j = j0; j < j0 + 4; ++j) {
            const bf16x8 b0 = *(const bf16x8*)(wq + (size_t)j * 2048);
            const bf16x8 b1 = *(const bf16x8*)(wq + (size_t)j * 2048 + 1024);
            acc0 = __builtin_amdgcn_mfma_f32_16x16x32_bf16(a[j], b0, acc0, 0, 0, 0);
            acc1 = __builtin_amdgcn_mfma_f32_16x16x32_bf16(a[j], b1, acc1, 0, 0, 0);
          }
        };
        asm volatile("s_waitcnt vmcnt(12)" ::: "memory");
        __builtin_amdgcn_sched_barrier(0);  // rule #18: keep MFMAs below their wait
        mm4(0);
        asm volatile("s_waitcnt vmcnt(8)" ::: "memory");
        __builtin_amdgcn_sched_barrier(0);
        mm4(4);
        asm volatile("s_waitcnt vmcnt(4)" ::: "memory");
        __builtin_amdgcn_sched_barrier(0);
        mm4(8);
        asm volatile("s_waitcnt vmcnt(0)" ::: "memory");
        __builtin_amdgcn_sched_barrier(0);
        mm4(12);
      } else {
#pragma unroll
        for (int j = 0; j < 16; ++j) {
          const bf16x8 b0 = *(const bf16x8*)(wq + (size_t)j * 2048);
          const bf16x8 b1 = *(const bf16x8*)(wq + (size_t)j * 2048 + 1024);
          acc0 = __builtin_amdgcn_mfma_f32_16x16x32_bf16(a[j], b0, acc0, 0, 0, 0);
          acc1 = __builtin_amdgcn_mfma_f32_16x16x32_bf16(a[j], b1, acc1, 0, 0, 0);
        }
      }

      // 4-way K-quarter reduction: kq>0 waves dump, kq==0 waves sum + bias -> gates
      if (kq > 0) {
        const int s0 = (((kq - 1) * 2 + tb) * 2 + 0) * 64 + lane;
        const int s1 = (((kq - 1) * 2 + tb) * 2 + 1) * 64 + lane;
        *(f32x4*)(red + s0 * 4) = acc0;
        *(f32x4*)(red + s1 * 4) = acc1;
      }
      __syncthreads();
      if (kq == 0) {
#pragma unroll
        for (int q = 1; q < 4; ++q) {
          const f32x4 o0 = *(const f32x4*)(red + ((((q - 1) * 2 + tb) * 2 + 0) * 64 + lane) * 4);
          const f32x4 o1 = *(const f32x4*)(red + ((((q - 1) * 2 + tb) * 2 + 1) * 64 + lane) * 4);
#pragma unroll
          for (int r = 0; r < 4; ++r) { acc0[r] += o0[r]; acc1[r] += o1[r]; }
        }
        const int rb = tb * 16 + kg * 4;
#pragma unroll
        for (int r = 0; r < 4; ++r) {
          gates[(rb + r) * 33 + cc] = acc0[r] + biasv0;
          gates[(rb + r) * 33 + 16 + cc] = acc1[r] + biasv1;
        }
      }
      __syncthreads();
      // cell update: 128 threads x 2 units; c-state in LDS; h stored as coherent dword
      if (tid < 128) {
        const int cb = tid >> 2, up = (tid & 3) * 2;
        const float gi0 = gates[cb * 33 + up],      gi1 = gates[cb * 33 + up + 1];
        const float gj0 = gates[cb * 33 + 8 + up],  gj1 = gates[cb * 33 + 9 + up];
        const float gf0 = gates[cb * 33 + 16 + up], gf1 = gates[cb * 33 + 17 + up];
        const float go0 = gates[cb * 33 + 24 + up], go1 = gates[cb * 33 + 25 + up];
        const float cn0 = cl[cb * 8 + up] * sigm(gf0) + sigm(gi0) * tanhf(gj0);
        const float cn1 = cl[cb * 8 + up + 1] * sigm(gf1) + sigm(gi1) * tanhf(gj1);
        const float hn0 = tanhf(cn0) * sigm(go0);
        const float hn1 = tanhf(cn1) * sigm(go1);
        cl[cb * 8 + up] = cn0;
        cl[cb * 8 + up + 1] = cn1;
        const unsigned int pk = cvt_pk_bf16(hn0, hn1);
        st_cv((unsigned int*)(hmy + ((p + 1) & 1) * 32768 + cb * 1024 + u0 + up), pk);
        if (layer) *(unsigned int*)(hseq + (size_t)t * 32768 + cb * 1024 + u0 + up) = pk;
        if (t == 127) {
          float* ot = out_tail + layer * 32768 + cb * 1024 + u0 + up;
          ot[0] = hn0; ot[1] = hn1;                     // h_last
          ot[65536] = cn0; ot[65537] = cn1;             // c_last
        }
      }
    }

    if (p < 128) {
      __syncthreads();  // all LDS consumers done; drains h stores (vmcnt 0) before arrive
      if (tid == 0) gbar_arrive(bar, p + 1, bid);
      if (statx && (p + 1) < 128) {
        // prefetch next-t xemb frags; they fly during the poll, land at exit syncthreads
        const char* xn = (const char*)xemb + (size_t)(p + 1) * 65536 + row * 2048 + kq * 1024 + kg * 16;
#pragma unroll
        for (int j = 0; j < 16; ++j) a[j] = *(const bf16x8*)(xn + j * 64);
      }
      if (tid == 0) gbar_wait(bar, p + 1);
      __syncthreads();
    }
  }
}

// ---------------- K4: dec_W [1024][32000] f32 -> Wt [32000][1024] bf16 ----------------
__global__ __launch_bounds__(256) void transpose_decw_kernel(
    const float* __restrict__ decW, unsigned short* __restrict__ Wt)
{
  __shared__ float tile[64 * 68];
  const int bid = blockIdx.x;         // 8000 = 16 k-tiles x 500 n-tiles
  const int k0 = (bid & 15) * 64;
  const int n0 = (bid >> 4) * 64;
  const int tid = threadIdx.x;
  {
    const int kl = tid >> 4, c4 = (tid & 15) * 4;
#pragma unroll
    for (int i = 0; i < 4; ++i) {
      const int kr = kl + 16 * i;
      *(float4*)(tile + kr * 68 + c4) =
          *(const float4*)(decW + (size_t)(k0 + kr) * 32000 + n0 + c4);
    }
  }
  __syncthreads();
  {
    const int nl = tid >> 3, kc = (tid & 7) * 8;
#pragma unroll
    for (int h2 = 0; h2 < 2; ++h2) {
      const int n = nl + 32 * h2;
      float tv[8];
#pragma unroll
      for (int q = 0; q < 8; ++q) tv[q] = tile[(kc + q) * 68 + n];
      uint4 u;
      u.x = cvt_pk_bf16(tv[0], tv[1]);
      u.y = cvt_pk_bf16(tv[2], tv[3]);
      u.z = cvt_pk_bf16(tv[4], tv[5]);
      u.w = cvt_pk_bf16(tv[6], tv[7]);
      *(uint4*)(Wt + (size_t)(n0 + n) * 1024 + k0 + kc) = u;
    }
  }
}

// ---------------- K5: decoder bf16 MFMA GEMM, 256x256 tile, BK=64, swizzled LDS ----------------
// 2000 blocks x 512 threads (8 waves = 2M x 4N), 2x64KB LDS dbuf, 1 block/CU.
__global__ __launch_bounds__(512, 1) void decoder_kernel(
    const unsigned short* __restrict__ A,   // hseq  [4096][1024] bf16
    const unsigned short* __restrict__ Bt,  // Wt    [32000][1024] bf16 (dec_W^T)
    const float* __restrict__ decb,
    float* __restrict__ out)                // [4096][32000] f32
{
  __shared__ __align__(16) char lds[131072];   // buf b at b*65536: A[256x64] then B[256x64]

  const int bid = blockIdx.x;
  const int swz = (bid & 7) * 250 + (bid >> 3);   // XCD-contiguous (2000 % 8 == 0)
  const int mt = swz / 125, nt = swz % 125;
  const int m0 = mt * 256, n0 = nt * 256;

  const int tid = threadIdx.x;
  const int lane = tid & 63;
  const int wv = tid >> 6;
  const int wm = wv >> 2, wn = wv & 3;            // 2M x 4N waves, out 128x64 each
  const int l15 = lane & 15, kg = lane >> 4;

  f32x4 acc[8][4];
#pragma unroll
  for (int mi = 0; mi < 8; ++mi)
#pragma unroll
    for (int ni = 0; ni < 4; ++ni) {
      f32x4 z = {0.f, 0.f, 0.f, 0.f};
      acc[mi][ni] = z;
    }

  // stage half of tile kt (half 0 = A 256x64, half 1 = B 256x64) into buf kt&1.
  // LDS dest linear; global source pre-swizzled by the st_16x32 involution.
  auto stage4 = [&](int kt, int half) {
    char* bufw = lds + (kt & 1) * 65536 + half * 32768;
    const unsigned short* base = half ? Bt : A;
    const int r0 = half ? n0 : m0;
#pragma unroll
    for (int j = 0; j < 4; ++j) {
      const int o  = (j * 512 + tid) * 16;            // 0..32752, linear LDS offset
      const int os = o ^ (((o >> 9) & 1) << 5);       // swizzled source index
      const int r  = os >> 7, kb = os & 127;          // row, k-byte within 128B row
      const unsigned short* g = base + (size_t)(r0 + r) * 1024 + kt * 64 + kb / 2;
      __builtin_amdgcn_global_load_lds((gas_ptr)g, (las_ptr)(bufw + o), 16, 0, 0);
    }
  };

  stage4(0, 0);
  stage4(0, 1);
  __syncthreads();   // drains vmcnt: tile0 in LDS

  for (int kt = 0; kt < 16; ++kt) {
    const char* bufr = lds + (kt & 1) * 65536;
    bf16x8 bfr[4];
#pragma unroll
    for (int ks = 0; ks < 2; ++ks) {
#pragma unroll
      for (int mh = 0; mh < 2; ++mh) {
        bf16x8 af[4];
#pragma unroll
        for (int q = 0; q < 4; ++q) {                 // A frags mi = mh*4+q
          const int r = wm * 128 + (mh * 4 + q) * 16 + l15;
          const int o = (r * 128 + ks * 64 + kg * 16) ^ (((r >> 2) & 1) << 5);
          af[q] = *(const bf16x8*)(bufr + o);
        }
        if (mh == 0) {
#pragma unroll
          for (int q = 0; q < 4; ++q) {               // B frags ni = q (reused for mh=1)
            const int r = wn * 64 + q * 16 + l15;
            const int o = (r * 128 + ks * 64 + kg * 16) ^ (((r >> 2) & 1) << 5);
            bfr[q] = *(const bf16x8*)(bufr + 32768 + o);
          }
        }
        if (ks == 0 && kt < 15) stage4(kt + 1, mh);   // issue next-tile stages early
        __builtin_amdgcn_s_setprio(1);
#pragma unroll
        for (int q = 0; q < 4; ++q)
#pragma unroll
          for (int ni = 0; ni < 4; ++ni)
            acc[mh * 4 + q][ni] =
                __builtin_amdgcn_mfma_f32_16x16x32_bf16(af[q], bfr[ni], acc[mh * 4 + q][ni], 0, 0, 0);
        __builtin_amdgcn_s_setprio(0);
      }
    }
    __syncthreads();  // per-tile: drains stage loads (vmcnt0) + protects buf swap
  }

#pragma unroll
  for (int ni = 0; ni < 4; ++ni) {
    const int ocol = n0 + wn * 64 + ni * 16 + l15;    // C/D: col = lane&15
    const float bv = decb[ocol];
#pragma unroll
    for (int mi = 0; mi < 8; ++mi) {
      const int orow = m0 + wm * 128 + mi * 16 + kg * 4;  // row = (lane>>4)*4 + reg
#pragma unroll
      for (int r = 0; r < 4; ++r)
        out[(size_t)(orow + r) * 32000 + ocol] = acc[mi][ni][r] + bv;
    }
  }
}

extern "C" void kernel_launch(void* const* d_in, const int* in_sizes, int n_in,
                              void* d_out, int out_size, void* d_ws, size_t ws_size,
                              hipStream_t stream) {
  (void)in_sizes; (void)n_in; (void)out_size; (void)ws_size;
  const int* tokens  = (const int*)d_in[0];
  const float* h0_in = (const float*)d_in[1];
  const float* c0_in = (const float*)d_in[2];
  const float* etab  = (const float*)d_in[3];
  const float* lstmW = (const float*)d_in[4];
  const float* lstmb = (const float*)d_in[5];
  const float* decW  = (const float*)d_in[6];
  const float* decb  = (const float*)d_in[7];
  float* out = (float*)d_out;

  char* ws = (char*)d_ws;
  unsigned short* hseq  = (unsigned short*)(ws + 0);         //  8,388,608 B
  char* img             = ws + 8388608;                      // 33,554,432 B (lstm phase)
  unsigned short* Wt    = (unsigned short*)(ws + 8388608);   // 65,536,000 B (decoder phase, overlaps img+xemb)
  unsigned short* xemb  = (unsigned short*)(ws + 41943040);  //  8,388,608 B (lstm phase)
  unsigned short* h0buf = (unsigned short*)(ws + 73924608);  //    131,072 B (bf16, 2 slots)
  unsigned short* h1buf = (unsigned short*)(ws + 74055680);  //    131,072 B
  int* bar              = (int*)(ws + 74186752);             //      3,072 B

  init_kernel<<<128, 256, 0, stream>>>(h0_in, h0buf, h1buf, bar);
  gather_emb<<<4096, 256, 0, stream>>>(tokens, etab, xemb);
  reorg_lstm_w<<<256, 256, 0, stream>>>(lstmW, img);
  lstm_seq_kernel<<<256, 512, 0, stream>>>(img, lstmb, c0_in, xemb,
                                           h0buf, h1buf, hseq,
                                           out + 131072000, bar);
  transpose_decw_kernel<<<8000, 256, 0, stream>>>(decW, Wt);
  decoder_kernel<<<2000, 512, 0, stream>>>(hseq, Wt, decb, out);
}

// Round 12
// 1257.612 us; speedup vs baseline: 1.1197x; 1.1114x over previous
//
#include <hip/hip_runtime.h>

typedef __attribute__((ext_vector_type(8))) short bf16x8;
typedef __attribute__((ext_vector_type(4))) float f32x4;
typedef const __attribute__((address_space(1))) void* gas_ptr;
typedef __attribute__((address_space(3))) void* las_ptr;

__device__ __forceinline__ unsigned short f2bf(float f) {
  unsigned int u = __float_as_uint(f);
  return (unsigned short)((u + 0x7fffu + ((u >> 16) & 1u)) >> 16);  // RNE
}
__device__ __forceinline__ unsigned int cvt_pk_bf16(float a, float b) {
  unsigned int r;
  asm volatile("v_cvt_pk_bf16_f32 %0, %1, %2" : "=v"(r) : "v"(a), "v"(b));
  return r;
}
__device__ __forceinline__ float sigm(float x) { return 1.0f / (1.0f + __expf(-x)); }

// device-coherent (sc0 sc1) store: relaxed agent atomic bypasses L1/L2, lands at IF.
__device__ __forceinline__ void st_cv(unsigned int* p, unsigned int v) {
  __hip_atomic_store(p, v, __ATOMIC_RELAXED, __HIP_MEMORY_SCOPE_AGENT);
}

// ---- fence-free two-level grid barrier (R9-measured optimum topology) ----
// 16 leaf lines (16 RMWs each, unpolled) -> master line (16 RMWs, unpolled) -> sense word
// (ONE plain store/phase; 256 thread-0 pollers). Polled line: single writer, single store,
// no RMW (R10/R11 lessons). All relaxed; __syncthreads drains stores before arrive.
__device__ __forceinline__ void gbar_arrive(int* bars, int target, int bid) {
  int* leaf  = bars + (bid & 15) * 32;
  int* mcnt  = bars + 512;
  int* sense = bars + 640;
  if (__hip_atomic_fetch_add(leaf, 1, __ATOMIC_RELAXED, __HIP_MEMORY_SCOPE_AGENT) == 15) {
    __hip_atomic_store(leaf, 0, __ATOMIC_RELAXED, __HIP_MEMORY_SCOPE_AGENT);
    if (__hip_atomic_fetch_add(mcnt, 1, __ATOMIC_RELAXED, __HIP_MEMORY_SCOPE_AGENT) == 15) {
      __hip_atomic_store(mcnt, 0, __ATOMIC_RELAXED, __HIP_MEMORY_SCOPE_AGENT);
      __hip_atomic_store(sense, target, __ATOMIC_RELAXED, __HIP_MEMORY_SCOPE_AGENT);
    }
  }
}
__device__ __forceinline__ void gbar_wait(int* bars, int target) {
  int* sense = bars + 640;
  while (__hip_atomic_load(sense, __ATOMIC_RELAXED, __HIP_MEMORY_SCOPE_AGENT) < target)
    __builtin_amdgcn_s_sleep(1);
}

// ---------------- K1: h0 -> bf16 double-buffered state, zero barrier ----------------
__global__ __launch_bounds__(256) void init_kernel(
    const float* __restrict__ h0_in,
    unsigned short* __restrict__ h0buf, unsigned short* __restrict__ h1buf,
    int* __restrict__ bar)
{
  const int j = blockIdx.x * 256 + threadIdx.x;   // 0..32767
  if (j < 768) bar[j] = 0;
  h0buf[j] = f2bf(h0_in[j]);                 // layer0 h -> h0buf slot0
  h1buf[32768 + j] = f2bf(h0_in[32768 + j]); // layer1 h -> h1buf slot1
}

// ---------------- K1b: gather emb[tokens] -> xemb bf16 [128*32][1024] ----------------
__global__ __launch_bounds__(256) void gather_emb(
    const int* __restrict__ tokens, const float* __restrict__ etab,
    unsigned short* __restrict__ xemb)
{
  const int r = blockIdx.x;                       // t*32 + b
  const float* src = etab + (size_t)tokens[r] * 1024;
  const int q = threadIdx.x * 4;
  const float4 v = *(const float4*)(src + q);
  uint2 o;
  o.x = cvt_pk_bf16(v.x, v.y);
  o.y = cvt_pk_bf16(v.z, v.w);
  *(uint2*)(xemb + (size_t)r * 1024 + q) = o;
}

// ---------------- K2: lstm_W -> per-block MFMA-fragment-slot images (bf16) ----------------
__global__ __launch_bounds__(256) void reorg_lstm_w(
    const float* __restrict__ W, char* __restrict__ wimg)
{
  __shared__ float tile[64 * 36];
  const int bid = blockIdx.x;            // 256 = lstm block id
  const int layer = bid >> 7;
  const int u0 = (bid & 127) * 8;
  const int tid = threadIdx.x;
  const float* Wl = W + (size_t)layer * 2048 * 4096;
  char* img = wimg + (size_t)bid * 131072;
  const int kl = tid >> 2, g = tid & 3;                                  // load map
  const int row = tid & 15, ksub = (tid >> 4) & 3;                       // emit map
  const int tn = (tid >> 6) & 1, kl2 = tid >> 7;
  const int c = tn * 16 + row;
#pragma unroll 1
  for (int kt = 0; kt < 32; ++kt) {
    const float* src = Wl + (size_t)(kt * 64 + kl) * 4096 + g * 1024 + u0;
    const float4 v0 = *(const float4*)src;
    const float4 v1 = *(const float4*)(src + 4);
    *(float4*)(tile + kl * 36 + g * 8) = v0;
    *(float4*)(tile + kl * 36 + g * 8 + 4) = v1;
    __syncthreads();
    const int kbase = kl2 * 32 + ksub * 8;
    uint4 u;
    u.x = cvt_pk_bf16(tile[(kbase + 0) * 36 + c], tile[(kbase + 1) * 36 + c]);
    u.y = cvt_pk_bf16(tile[(kbase + 2) * 36 + c], tile[(kbase + 3) * 36 + c]);
    u.z = cvt_pk_bf16(tile[(kbase + 4) * 36 + c], tile[(kbase + 5) * 36 + c]);
    u.w = cvt_pk_bf16(tile[(kbase + 6) * 36 + c], tile[(kbase + 7) * 36 + c]);
    const int S = (kt * 2 + kl2) * 128 + tn * 64 + ksub * 16 + row;
    *(uint4*)(img + (size_t)S * 16) = u;
    __syncthreads();
  }
}

// ---------------- K3: pipelined 2-layer LSTM scan (R9 structure + barrier) ----------------
__global__ __launch_bounds__(512, 1) void lstm_seq_kernel(
    const char* __restrict__ wimg, const float* __restrict__ bias,
    const float* __restrict__ c0_in,
    const unsigned short* __restrict__ xemb,
    unsigned short* __restrict__ h0buf, unsigned short* __restrict__ h1buf,
    unsigned short* __restrict__ hseq,
    float* __restrict__ out_tail, int* __restrict__ bar)
{
  __shared__ __align__(16) char smem[148608];
  char* wlds   = smem;                        // 131072: W fragment slots
  float* red   = (float*)(smem + 131072);     //  12288: K-quarter partials
  float* gates = (float*)(smem + 143360);     //   4224: [32 b][33] padded
  float* cl    = (float*)(smem + 147584);     //   1024: c-state [32 b][8 u]

  const int tid = threadIdx.x;
  const int bid = blockIdx.x;
  const int layer = bid >> 7;
  const int u0 = (bid & 127) * 8;
  const int lane = tid & 63, w = tid >> 6;
  const int tb = w & 1, kq = w >> 1;
  const int row = tb * 16 + (lane & 15);
  const int kg = lane >> 4;
  unsigned short* hmy = layer ? h1buf : h0buf;
  const bool statx = (layer == 0) && (kq < 2);   // static xemb operand (prefetchable)

  // one-time: W image -> LDS (linear 16B, coalesced), c-state -> LDS
  {
    const char* img = wimg + (size_t)bid * 131072;
#pragma unroll 1
    for (int i = 0; i < 16; ++i) {
      const int off = (i * 512 + tid) * 16;
      __builtin_amdgcn_global_load_lds((gas_ptr)(img + off), (las_ptr)(wlds + off), 16, 0, 0);
    }
    if (tid < 256) cl[tid] = c0_in[layer * 32768 + (tid >> 3) * 1024 + u0 + (tid & 7)];
  }
  const int cc = lane & 15;
  const float biasv0 = bias[layer * 4096 + (cc >> 3) * 1024 + u0 + (cc & 7)];         // tn=0 col
  const float biasv1 = bias[layer * 4096 + ((cc + 16) >> 3) * 1024 + u0 + (cc & 7)];  // tn=1 col
  asm volatile("s_waitcnt vmcnt(0)");
  __syncthreads();

  const char* wq = wlds + (size_t)(kq * 16 * 128 + lane) * 16;

  bf16x8 a[16];
  if (statx) {  // prefetch t=0 fragments (plain cached loads; xemb is static)
    const char* xn = (const char*)xemb + row * 2048 + kq * 1024 + kg * 16;
#pragma unroll
    for (int j = 0; j < 16; ++j) a[j] = *(const bf16x8*)(xn + j * 64);
  }

  for (int p = 0; p <= 128; ++p) {
    const bool active = layer ? (p >= 1) : (p < 128);
    if (active) {
      const int t = layer ? (p - 1) : p;
      f32x4 acc0 = {0.f, 0.f, 0.f, 0.f}, acc1 = {0.f, 0.f, 0.f, 0.f};

      if (!statx) {
        // coherent x: layer0 kq>=2 -> own h0; layer1: kq<2 -> h0, kq>=2 -> own h1
        const char* src = (layer && kq < 2) ? (const char*)h0buf : (const char*)hmy;
        const char* xb = src + (p & 1) * 65536 + row * 2048 + (kq & 1) * 1024 + kg * 16;
#pragma unroll
        for (int j = 0; j < 16; ++j)
          asm volatile("global_load_dwordx4 %0, %1, off sc0 sc1"
                       : "=v"(a[j]) : "v"(xb + j * 64) : "memory");
        auto mm4 = [&](int j0) {
#pragma unroll
          for (int j = j0; j < j0 + 4; ++j) {
            const bf16x8 b0 = *(const bf16x8*)(wq + (size_t)j * 2048);
            const bf16x8 b1 = *(const bf16x8*)(wq + (size_t)j * 2048 + 1024);
            acc0 = __builtin_amdgcn_mfma_f32_16x16x32_bf16(a[j], b0, acc0, 0, 0, 0);
            acc1 = __builtin_amdgcn_mfma_f32_16x16x32_bf16(a[j], b1, acc1, 0, 0, 0);
          }
        };
        asm volatile("s_waitcnt vmcnt(12)" ::: "memory");
        __builtin_amdgcn_sched_barrier(0);  // rule #18: keep MFMAs below their wait
        mm4(0);
        asm volatile("s_waitcnt vmcnt(8)" ::: "memory");
        __builtin_amdgcn_sched_barrier(0);
        mm4(4);
        asm volatile("s_waitcnt vmcnt(4)" ::: "memory");
        __builtin_amdgcn_sched_barrier(0);
        mm4(8);
        asm volatile("s_waitcnt vmcnt(0)" ::: "memory");
        __builtin_amdgcn_sched_barrier(0);
        mm4(12);
      } else {
#pragma unroll
        for (int j = 0; j < 16; ++j) {
          const bf16x8 b0 = *(const bf16x8*)(wq + (size_t)j * 2048);
          const bf16x8 b1 = *(const bf16x8*)(wq + (size_t)j * 2048 + 1024);
          acc0 = __builtin_amdgcn_mfma_f32_16x16x32_bf16(a[j], b0, acc0, 0, 0, 0);
          acc1 = __builtin_amdgcn_mfma_f32_16x16x32_bf16(a[j], b1, acc1, 0, 0, 0);
        }
      }

      // 4-way K-quarter reduction: kq>0 waves dump, kq==0 waves sum + bias -> gates
      if (kq > 0) {
        const int s0 = (((kq - 1) * 2 + tb) * 2 + 0) * 64 + lane;
        const int s1 = (((kq - 1) * 2 + tb) * 2 + 1) * 64 + lane;
        *(f32x4*)(red + s0 * 4) = acc0;
        *(f32x4*)(red + s1 * 4) = acc1;
      }
      __syncthreads();
      if (kq == 0) {
#pragma unroll
        for (int q = 1; q < 4; ++q) {
          const f32x4 o0 = *(const f32x4*)(red + ((((q - 1) * 2 + tb) * 2 + 0) * 64 + lane) * 4);
          const f32x4 o1 = *(const f32x4*)(red + ((((q - 1) * 2 + tb) * 2 + 1) * 64 + lane) * 4);
#pragma unroll
          for (int r = 0; r < 4; ++r) { acc0[r] += o0[r]; acc1[r] += o1[r]; }
        }
        const int rb = tb * 16 + kg * 4;
#pragma unroll
        for (int r = 0; r < 4; ++r) {
          gates[(rb + r) * 33 + cc] = acc0[r] + biasv0;
          gates[(rb + r) * 33 + 16 + cc] = acc1[r] + biasv1;
        }
      }
      __syncthreads();
      // cell update: 128 threads x 2 units; c-state in LDS; h stored as coherent dword
      if (tid < 128) {
        const int cb = tid >> 2, up = (tid & 3) * 2;
        const float gi0 = gates[cb * 33 + up],      gi1 = gates[cb * 33 + up + 1];
        const float gj0 = gates[cb * 33 + 8 + up],  gj1 = gates[cb * 33 + 9 + up];
        const float gf0 = gates[cb * 33 + 16 + up], gf1 = gates[cb * 33 + 17 + up];
        const float go0 = gates[cb * 33 + 24 + up], go1 = gates[cb * 33 + 25 + up];
        const float cn0 = cl[cb * 8 + up] * sigm(gf0) + sigm(gi0) * tanhf(gj0);
        const float cn1 = cl[cb * 8 + up + 1] * sigm(gf1) + sigm(gi1) * tanhf(gj1);
        const float hn0 = tanhf(cn0) * sigm(go0);
        const float hn1 = tanhf(cn1) * sigm(go1);
        cl[cb * 8 + up] = cn0;
        cl[cb * 8 + up + 1] = cn1;
        const unsigned int pk = cvt_pk_bf16(hn0, hn1);
        st_cv((unsigned int*)(hmy + ((p + 1) & 1) * 32768 + cb * 1024 + u0 + up), pk);
        if (layer) *(unsigned int*)(hseq + (size_t)t * 32768 + cb * 1024 + u0 + up) = pk;
        if (t == 127) {
          float* ot = out_tail + layer * 32768 + cb * 1024 + u0 + up;
          ot[0] = hn0; ot[1] = hn1;                     // h_last
          ot[65536] = cn0; ot[65537] = cn1;             // c_last
        }
      }
    }

    if (p < 128) {
      __syncthreads();  // all LDS consumers done; drains h stores (vmcnt 0) before arrive
      if (tid == 0) gbar_arrive(bar, p + 1, bid);
      if (statx && (p + 1) < 128) {
        // prefetch next-t xemb frags; they fly during the poll, land at exit syncthreads
        const char* xn = (const char*)xemb + (size_t)(p + 1) * 65536 + row * 2048 + kq * 1024 + kg * 16;
#pragma unroll
        for (int j = 0; j < 16; ++j) a[j] = *(const bf16x8*)(xn + j * 64);
      }
      if (tid == 0) gbar_wait(bar, p + 1);
      __syncthreads();
    }
  }
}

// ---------------- K4: dec_W [1024][32000] f32 -> Wt [32000][1024] bf16 ----------------
__global__ __launch_bounds__(256) void transpose_decw_kernel(
    const float* __restrict__ decW, unsigned short* __restrict__ Wt)
{
  __shared__ float tile[64 * 68];
  const int bid = blockIdx.x;         // 8000 = 16 k-tiles x 500 n-tiles
  const int k0 = (bid & 15) * 64;
  const int n0 = (bid >> 4) * 64;
  const int tid = threadIdx.x;
  {
    const int kl = tid >> 4, c4 = (tid & 15) * 4;
#pragma unroll
    for (int i = 0; i < 4; ++i) {
      const int kr = kl + 16 * i;
      *(float4*)(tile + kr * 68 + c4) =
          *(const float4*)(decW + (size_t)(k0 + kr) * 32000 + n0 + c4);
    }
  }
  __syncthreads();
  {
    const int nl = tid >> 3, kc = (tid & 7) * 8;
#pragma unroll
    for (int h2 = 0; h2 < 2; ++h2) {
      const int n = nl + 32 * h2;
      float tv[8];
#pragma unroll
      for (int q = 0; q < 8; ++q) tv[q] = tile[(kc + q) * 68 + n];
      uint4 u;
      u.x = cvt_pk_bf16(tv[0], tv[1]);
      u.y = cvt_pk_bf16(tv[2], tv[3]);
      u.z = cvt_pk_bf16(tv[4], tv[5]);
      u.w = cvt_pk_bf16(tv[6], tv[7]);
      *(uint4*)(Wt + (size_t)(n0 + n) * 1024 + k0 + kc) = u;
    }
  }
}

// ---------------- K5: decoder bf16 MFMA GEMM, 256x256 tile, BK=64, swizzled LDS ----------------
// 2000 blocks x 512 threads (8 waves = 2M x 4N), 2x64KB LDS dbuf, 1 block/CU.
__global__ __launch_bounds__(512, 1) void decoder_kernel(
    const unsigned short* __restrict__ A,   // hseq  [4096][1024] bf16
    const unsigned short* __restrict__ Bt,  // Wt    [32000][1024] bf16 (dec_W^T)
    const float* __restrict__ decb,
    float* __restrict__ out)                // [4096][32000] f32
{
  __shared__ __align__(16) char lds[131072];   // buf b at b*65536: A[256x64] then B[256x64]

  const int bid = blockIdx.x;
  const int swz = (bid & 7) * 250 + (bid >> 3);   // XCD-contiguous (2000 % 8 == 0)
  const int mt = swz / 125, nt = swz % 125;
  const int m0 = mt * 256, n0 = nt * 256;

  const int tid = threadIdx.x;
  const int lane = tid & 63;
  const int wv = tid >> 6;
  const int wm = wv >> 2, wn = wv & 3;            // 2M x 4N waves, out 128x64 each
  const int l15 = lane & 15, kg = lane >> 4;

  f32x4 acc[8][4];
#pragma unroll
  for (int mi = 0; mi < 8; ++mi)
#pragma unroll
    for (int ni = 0; ni < 4; ++ni) {
      f32x4 z = {0.f, 0.f, 0.f, 0.f};
      acc[mi][ni] = z;
    }

  // stage half of tile kt (half 0 = A 256x64, half 1 = B 256x64) into buf kt&1.
  // LDS dest linear; global source pre-swizzled by the st_16x32 involution.
  auto stage4 = [&](int kt, int half) {
    char* bufw = lds + (kt & 1) * 65536 + half * 32768;
    const unsigned short* base = half ? Bt : A;
    const int r0 = half ? n0 : m0;
#pragma unroll
    for (int j = 0; j < 4; ++j) {
      const int o  = (j * 512 + tid) * 16;            // 0..32752, linear LDS offset
      const int os = o ^ (((o >> 9) & 1) << 5);       // swizzled source index
      const int r  = os >> 7, kb = os & 127;          // row, k-byte within 128B row
      const unsigned short* g = base + (size_t)(r0 + r) * 1024 + kt * 64 + kb / 2;
      __builtin_amdgcn_global_load_lds((gas_ptr)g, (las_ptr)(bufw + o), 16, 0, 0);
    }
  };

  stage4(0, 0);
  stage4(0, 1);
  __syncthreads();   // drains vmcnt: tile0 in LDS

  for (int kt = 0; kt < 16; ++kt) {
    const char* bufr = lds + (kt & 1) * 65536;
    bf16x8 bfr[4];
#pragma unroll
    for (int ks = 0; ks < 2; ++ks) {
#pragma unroll
      for (int mh = 0; mh < 2; ++mh) {
        bf16x8 af[4];
#pragma unroll
        for (int q = 0; q < 4; ++q) {                 // A frags mi = mh*4+q
          const int r = wm * 128 + (mh * 4 + q) * 16 + l15;
          const int o = (r * 128 + ks * 64 + kg * 16) ^ (((r >> 2) & 1) << 5);
          af[q] = *(const bf16x8*)(bufr + o);
        }
        if (mh == 0) {
#pragma unroll
          for (int q = 0; q < 4; ++q) {               // B frags ni = q (reused for mh=1)
            const int r = wn * 64 + q * 16 + l15;
            const int o = (r * 128 + ks * 64 + kg * 16) ^ (((r >> 2) & 1) << 5);
            bfr[q] = *(const bf16x8*)(bufr + 32768 + o);
          }
        }
        if (ks == 0 && kt < 15) stage4(kt + 1, mh);   // issue next-tile stages early
        __builtin_amdgcn_s_setprio(1);
#pragma unroll
        for (int q = 0; q < 4; ++q)
#pragma unroll
          for (int ni = 0; ni < 4; ++ni)
            acc[mh * 4 + q][ni] =
                __builtin_amdgcn_mfma_f32_16x16x32_bf16(af[q], bfr[ni], acc[mh * 4 + q][ni], 0, 0, 0);
        __builtin_amdgcn_s_setprio(0);
      }
    }
    __syncthreads();  // per-tile: drains stage loads (vmcnt0) + protects buf swap
  }

#pragma unroll
  for (int ni = 0; ni < 4; ++ni) {
    const int ocol = n0 + wn * 64 + ni * 16 + l15;    // C/D: col = lane&15
    const float bv = decb[ocol];
#pragma unroll
    for (int mi = 0; mi < 8; ++mi) {
      const int orow = m0 + wm * 128 + mi * 16 + kg * 4;  // row = (lane>>4)*4 + reg
#pragma unroll
      for (int r = 0; r < 4; ++r)
        out[(size_t)(orow + r) * 32000 + ocol] = acc[mi][ni][r] + bv;
    }
  }
}

extern "C" void kernel_launch(void* const* d_in, const int* in_sizes, int n_in,
                              void* d_out, int out_size, void* d_ws, size_t ws_size,
                              hipStream_t stream) {
  (void)in_sizes; (void)n_in; (void)out_size; (void)ws_size;
  const int* tokens  = (const int*)d_in[0];
  const float* h0_in = (const float*)d_in[1];
  const float* c0_in = (const float*)d_in[2];
  const float* etab  = (const float*)d_in[3];
  const float* lstmW = (const float*)d_in[4];
  const float* lstmb = (const float*)d_in[5];
  const float* decW  = (const float*)d_in[6];
  const float* decb  = (const float*)d_in[7];
  float* out = (float*)d_out;

  char* ws = (char*)d_ws;
  unsigned short* hseq  = (unsigned short*)(ws + 0);         //  8,388,608 B
  char* img             = ws + 8388608;                      // 33,554,432 B (lstm phase)
  unsigned short* Wt    = (unsigned short*)(ws + 8388608);   // 65,536,000 B (decoder phase, overlaps img+xemb)
  unsigned short* xemb  = (unsigned short*)(ws + 41943040);  //  8,388,608 B (lstm phase)
  unsigned short* h0buf = (unsigned short*)(ws + 73924608);  //    131,072 B (bf16, 2 slots)
  unsigned short* h1buf = (unsigned short*)(ws + 74055680);  //    131,072 B
  int* bar              = (int*)(ws + 74186752);             //      3,072 B

  init_kernel<<<128, 256, 0, stream>>>(h0_in, h0buf, h1buf, bar);
  gather_emb<<<4096, 256, 0, stream>>>(tokens, etab, xemb);
  reorg_lstm_w<<<256, 256, 0, stream>>>(lstmW, img);
  lstm_seq_kernel<<<256, 512, 0, stream>>>(img, lstmb, c0_in, xemb,
                                           h0buf, h1buf, hseq,
                                           out + 131072000, bar);
  transpose_decw_kernel<<<8000, 256, 0, stream>>>(decW, Wt);
  decoder_kernel<<<2000, 512, 0, stream>>>(hseq, Wt, decb, out);
}